// Round 4
// baseline (314.609 us; speedup 1.0000x reference)
//
#include <hip/hip_runtime.h>
#include <hip/hip_bf16.h>
#include <math.h>

#define NNODES 100000
#define NEDGES 800000
#define HDIM 64
#define CDIM 10
#define NLAYERS 3
#define NGRAPH 500
#define BN_EPS 1e-5f
#define TN 64                       // nodes per fused-layer block tile
#define NBLK ((NNODES + 255) / 256) // scan blocks = 391

// ---------------- compact CSR build: histogram -> scan -> scatter -------------------
__global__ void hist_dst(const int* __restrict__ dst, unsigned* __restrict__ cnt) {
    int e = blockIdx.x * blockDim.x + threadIdx.x;
    if (e < NEDGES) atomicAdd(&cnt[dst[e]], 1u);
}

__global__ void scan_local(const unsigned* __restrict__ cnt, unsigned* __restrict__ row_off,
                           unsigned* __restrict__ bsum) {
    __shared__ unsigned s[256];
    int t = threadIdx.x;
    int i = blockIdx.x * 256 + t;
    unsigned v = (i < NNODES) ? cnt[i] : 0u;
    s[t] = v; __syncthreads();
    #pragma unroll
    for (int off = 1; off < 256; off <<= 1) {
        unsigned u = (t >= off) ? s[t - off] : 0u;
        __syncthreads();
        s[t] += u;
        __syncthreads();
    }
    if (i < NNODES) row_off[i] = s[t] - v;          // exclusive within block
    if (t == 255) bsum[blockIdx.x] = s[255];
}

__global__ void scan_bsums(unsigned* __restrict__ bsum) {
    __shared__ unsigned s[512];
    int t = threadIdx.x;
    unsigned v = (t < NBLK) ? bsum[t] : 0u;
    s[t] = v; __syncthreads();
    #pragma unroll
    for (int off = 1; off < 512; off <<= 1) {
        unsigned u = (t >= off) ? s[t - off] : 0u;
        __syncthreads();
        s[t] += u;
        __syncthreads();
    }
    if (t < NBLK) bsum[t] = s[t] - v;               // exclusive
}

__global__ void scan_add(unsigned* __restrict__ row_off, const unsigned* __restrict__ bsum,
                         unsigned* __restrict__ cursor) {
    int i = blockIdx.x * 256 + threadIdx.x;
    if (i < NNODES) {
        unsigned v = row_off[i] + bsum[blockIdx.x];
        row_off[i] = v;
        cursor[i] = v;
    }
}

__global__ void scatter_edges(const int* __restrict__ src, const int* __restrict__ dst,
                              unsigned* __restrict__ cursor, int* __restrict__ edge_src) {
    int e = blockIdx.x * blockDim.x + threadIdx.x;
    if (e >= NEDGES) return;
    unsigned pos = atomicAdd(&cursor[dst[e]], 1u);
    edge_src[pos] = src[e];
}

// ------- fused layer: gather-aggregate into LDS, then 64x64 GEMM + BN + ELU ---------
__global__ __launch_bounds__(256, 4) void layer_fused(
        const float* __restrict__ hin, const unsigned* __restrict__ row_off,
        const unsigned* __restrict__ cnt, const int* __restrict__ edge_src,
        const float* __restrict__ Ws, const float* __restrict__ bs,
        const float* __restrict__ gammas, const float* __restrict__ betas,
        const float* __restrict__ means, const float* __restrict__ vars_,
        int layer, float* __restrict__ hout) {
    __shared__ float Ml[TN][68];      // pad 68: 2-way worst alias on b128 (free)
    __shared__ float Wl[HDIM][68];
    int tid = threadIdx.x;

    // stage W (64x64), coalesced float4
    const float4* Wg4 = (const float4*)(Ws + (size_t)layer*HDIM*HDIM);
    #pragma unroll
    for (int r = 0; r < 4; ++r) {
        int f = tid + 256*r;
        int row = f >> 4, c4 = f & 15;
        *(float4*)&Wl[row][c4*4] = Wg4[f];
    }

    // aggregate phase: 16-lane group per node row, float4 per lane
    int base = blockIdx.x * TN;
    int g   = tid >> 4;               // 0..15
    int sub = tid & 15;               // float4 column
    const float4* h4 = (const float4*)hin;
    #pragma unroll
    for (int i = 0; i < 4; ++i) {
        int row = g + 16*i;
        int node = base + row;
        float4 acc = make_float4(0.f, 0.f, 0.f, 0.f);
        if (node < NNODES) {
            unsigned start = row_off[node];
            unsigned deg   = cnt[node];
            const int* ed = edge_src + start;
            unsigned e = 0;
            for (; e + 4 <= deg; e += 4) {
                int s0 = ed[e], s1 = ed[e+1], s2 = ed[e+2], s3 = ed[e+3];
                float4 v0 = h4[(size_t)s0*16 + sub];
                float4 v1 = h4[(size_t)s1*16 + sub];
                float4 v2 = h4[(size_t)s2*16 + sub];
                float4 v3 = h4[(size_t)s3*16 + sub];
                acc.x += v0.x + v1.x + v2.x + v3.x;
                acc.y += v0.y + v1.y + v2.y + v3.y;
                acc.z += v0.z + v1.z + v2.z + v3.z;
                acc.w += v0.w + v1.w + v2.w + v3.w;
            }
            for (; e < deg; ++e) {
                float4 v = h4[(size_t)ed[e]*16 + sub];
                acc.x += v.x; acc.y += v.y; acc.z += v.z; acc.w += v.w;
            }
        }
        *(float4*)&Ml[row][sub*4] = acc;
    }
    __syncthreads();

    // GEMM phase: 4x4 per thread
    int tx = tid & 15;        // node rows tx + 16*i
    int ty = tid >> 4;        // cols 4*ty .. 4*ty+3
    float acc[4][4];
    #pragma unroll
    for (int i = 0; i < 4; ++i)
        #pragma unroll
        for (int j = 0; j < 4; ++j) acc[i][j] = 0.f;

    #pragma unroll 4
    for (int k4 = 0; k4 < 16; ++k4) {
        float4 b0 = *(const float4*)&Wl[4*k4+0][ty*4];
        float4 b1 = *(const float4*)&Wl[4*k4+1][ty*4];
        float4 b2 = *(const float4*)&Wl[4*k4+2][ty*4];
        float4 b3 = *(const float4*)&Wl[4*k4+3][ty*4];
        #pragma unroll
        for (int i = 0; i < 4; ++i) {
            float4 a = *(const float4*)&Ml[tx + 16*i][k4*4];
            acc[i][0] += a.x*b0.x + a.y*b1.x + a.z*b2.x + a.w*b3.x;
            acc[i][1] += a.x*b0.y + a.y*b1.y + a.z*b2.y + a.w*b3.y;
            acc[i][2] += a.x*b0.z + a.y*b1.z + a.z*b2.z + a.w*b3.z;
            acc[i][3] += a.x*b0.w + a.y*b1.w + a.z*b2.w + a.w*b3.w;
        }
    }

    // epilogue: BN folded scale/shift + ELU
    float sc[4], sh[4];
    #pragma unroll
    for (int j = 0; j < 4; ++j) {
        int c = ty*4 + j;
        float b  = bs[layer*HDIM + c];
        float gm = gammas[layer*HDIM + c];
        float be = betas[layer*HDIM + c];
        float mu = means[layer*HDIM + c];
        float vv = vars_[layer*HDIM + c];
        float s  = gm * rsqrtf(vv + BN_EPS);
        sc[j] = s;
        sh[j] = (b - mu) * s + be;
    }
    float4* H4 = (float4*)hout;
    #pragma unroll
    for (int i = 0; i < 4; ++i) {
        int node = base + tx + 16*i;
        if (node >= NNODES) continue;
        float4 o;
        float y0 = acc[i][0]*sc[0] + sh[0]; o.x = (y0 > 0.f) ? y0 : expm1f(y0);
        float y1 = acc[i][1]*sc[1] + sh[1]; o.y = (y1 > 0.f) ? y1 : expm1f(y1);
        float y2 = acc[i][2]*sc[2] + sh[2]; o.z = (y2 > 0.f) ? y2 : expm1f(y2);
        float y3 = acc[i][3]*sc[3] + sh[3]; o.w = (y3 > 0.f) ? y3 : expm1f(y3);
        H4[(size_t)node*16 + ty] = o;
    }
}

// ---------------- logits -> entropy per node + global max ---------------------------
__global__ void classify(const float* __restrict__ H, const float* __restrict__ Wc,
                         const float* __restrict__ bc, float* __restrict__ Hent,
                         unsigned* __restrict__ maxH) {
    __shared__ float Wl[HDIM*CDIM];
    __shared__ float bl[CDIM];
    int tid = threadIdx.x;
    for (int idx = tid; idx < HDIM*CDIM; idx += blockDim.x) Wl[idx] = Wc[idx];
    if (tid < CDIM) bl[tid] = bc[tid];
    __syncthreads();

    int i = blockIdx.x * blockDim.x + tid;
    if (i >= NNODES) return;
    const float4* hr = (const float4*)(H + (size_t)i*HDIM);
    float lg[CDIM];
    #pragma unroll
    for (int c = 0; c < CDIM; ++c) lg[c] = bl[c];
    #pragma unroll
    for (int q = 0; q < HDIM/4; ++q) {
        float4 v = hr[q];
        #pragma unroll
        for (int kk = 0; kk < 4; ++kk) {
            float x = (&v.x)[kk];
            int k = q*4 + kk;
            #pragma unroll
            for (int c = 0; c < CDIM; ++c) lg[c] += x * Wl[k*CDIM + c];
        }
    }
    float mx = lg[0];
    #pragma unroll
    for (int c = 1; c < CDIM; ++c) mx = fmaxf(mx, lg[c]);
    float se = 0.f, dot = 0.f;
    #pragma unroll
    for (int c = 0; c < CDIM; ++c) { float e = expf(lg[c]-mx); se += e; dot += e*lg[c]; }
    float lse = mx + logf(se);
    float Hv = lse - dot/se;
    Hv = fmaxf(Hv, 0.f);
    Hent[i] = Hv;
    atomicMax(maxH, __float_as_uint(Hv));
}

// ---------------- per-graph lambda-weighted pooling + final classify ----------------
__global__ void pool_final(const float* __restrict__ H, const float* __restrict__ Hent,
                           const unsigned* __restrict__ maxH, const int* __restrict__ n2g,
                           const float* __restrict__ Wc, const float* __restrict__ bc,
                           float* __restrict__ out) {
    __shared__ float partial[4][HDIM];
    __shared__ float pooled[HDIM];
    int g = blockIdx.x;
    int w = threadIdx.x >> 6, lane = threadIdx.x & 63;

    int lo = 0, hi = NNODES;
    while (lo < hi) { int mid = (lo+hi) >> 1; if (n2g[mid] < g) lo = mid+1; else hi = mid; }
    int start = lo;
    hi = NNODES;
    while (lo < hi) { int mid = (lo+hi) >> 1; if (n2g[mid] < g+1) lo = mid+1; else hi = mid; }
    int end = lo;

    float invMax = 1.0f / __uint_as_float(*maxH);
    float acc = 0.f;
    for (int i = start + w; i < end; i += 4) {
        float lam = 1.0f - Hent[i] * invMax;
        acc += lam * H[(size_t)i*HDIM + lane];
    }
    partial[w][lane] = acc;
    __syncthreads();
    if (w == 0)
        pooled[lane] = partial[0][lane] + partial[1][lane] + partial[2][lane] + partial[3][lane];
    __syncthreads();
    if (threadIdx.x < CDIM) {
        int c = threadIdx.x;
        float s = bc[c];
        for (int k = 0; k < HDIM; ++k) s += pooled[k] * Wc[k*CDIM + c];
        out[g*CDIM + c] = s;
    }
}

extern "C" void kernel_launch(void* const* d_in, const int* in_sizes, int n_in,
                              void* d_out, int out_size, void* d_ws, size_t ws_size,
                              hipStream_t stream) {
    const float* feat  = (const float*)d_in[0];
    const int*   src   = (const int*)d_in[1];
    const int*   dst   = (const int*)d_in[2];
    const int*   n2g   = (const int*)d_in[3];
    const float* Ws    = (const float*)d_in[4];
    const float* bs    = (const float*)d_in[5];
    const float* gam   = (const float*)d_in[6];
    const float* bet   = (const float*)d_in[7];
    const float* mea   = (const float*)d_in[8];
    const float* var_  = (const float*)d_in[9];
    const float* Wc    = (const float*)d_in[10];
    const float* bc    = (const float*)d_in[11];
    float* out = (float*)d_out;

    char* ws = (char*)d_ws;
    size_t off = 0;
    auto take = [&](size_t bytes) {
        char* p = ws + off;
        off += (bytes + 255) & ~(size_t)255;
        return p;
    };

    unsigned* cnt     = (unsigned*)take((size_t)NNODES*4);
    unsigned* row_off = (unsigned*)take((size_t)NNODES*4);
    unsigned* cursor  = (unsigned*)take((size_t)NNODES*4);
    unsigned* bsum    = (unsigned*)take((size_t)512*4);
    unsigned* maxH    = (unsigned*)take(4);
    int*      edge_src= (int*)take((size_t)NEDGES*4);
    float*    HA      = (float*)take((size_t)NNODES*HDIM*4);
    float*    HB      = (float*)take((size_t)NNODES*HDIM*4);
    float*    Hent    = (float*)take((size_t)NNODES*4);

    hipMemsetAsync(maxH, 0, 4, stream);
    hipMemsetAsync(cnt, 0, (size_t)NNODES*4, stream);

    // compact CSR build
    hist_dst<<<(NEDGES+255)/256, 256, 0, stream>>>(dst, cnt);
    scan_local<<<NBLK, 256, 0, stream>>>(cnt, row_off, bsum);
    scan_bsums<<<1, 512, 0, stream>>>(bsum);
    scan_add<<<NBLK, 256, 0, stream>>>(row_off, bsum, cursor);
    scatter_edges<<<(NEDGES+255)/256, 256, 0, stream>>>(src, dst, cursor, edge_src);

    int grid = (NNODES + TN - 1) / TN;
    layer_fused<<<grid, 256, 0, stream>>>(feat, row_off, cnt, edge_src,
                                          Ws, bs, gam, bet, mea, var_, 0, HA);
    layer_fused<<<grid, 256, 0, stream>>>(HA, row_off, cnt, edge_src,
                                          Ws, bs, gam, bet, mea, var_, 1, HB);
    layer_fused<<<grid, 256, 0, stream>>>(HB, row_off, cnt, edge_src,
                                          Ws, bs, gam, bet, mea, var_, 2, HA);

    classify<<<(NNODES+255)/256, 256, 0, stream>>>(HA, Wc, bc, Hent, maxH);
    pool_final<<<NGRAPH, 256, 0, stream>>>(HA, Hent, maxH, n2g, Wc, bc, out);
}

// Round 5
// 241.855 us; speedup vs baseline: 1.3008x; 1.3008x over previous
//
#include <hip/hip_runtime.h>
#include <hip/hip_bf16.h>
#include <math.h>

#define NNODES 100000
#define NEDGES 800000
#define HDIM 64
#define CDIM 10
#define NGRAPH 500
#define CAP 40
#define OVFCAP 4096
#define BN_EPS 1e-5f
#define TN 64

__device__ __forceinline__ float bflo(unsigned u){ return __uint_as_float(u << 16); }
__device__ __forceinline__ float bfhi(unsigned u){ return __uint_as_float(u & 0xFFFF0000u); }
__device__ __forceinline__ unsigned f2bf(float f){
    unsigned u = __float_as_uint(f);
    u += 0x7FFFu + ((u >> 16) & 1u);          // RNE
    return u >> 16;
}

// ---------------- feat fp32 -> bf16 packed ------------------------------------------
__global__ void cvt_feat(const float4* __restrict__ F, uint4* __restrict__ B) {
    int i = blockIdx.x * 256 + threadIdx.x;   // exactly N*H/8 threads
    float4 a = F[2*i], b = F[2*i+1];
    uint4 o;
    o.x = f2bf(a.x) | (f2bf(a.y) << 16);
    o.y = f2bf(a.z) | (f2bf(a.w) << 16);
    o.z = f2bf(b.x) | (f2bf(b.y) << 16);
    o.w = f2bf(b.z) | (f2bf(b.w) << 16);
    B[i] = o;
}

// ---------------- bucketed CSR build (single kernel) --------------------------------
__global__ void fill_buckets(const int* __restrict__ src, const int* __restrict__ dst,
                             unsigned* __restrict__ cnt, int* __restrict__ csr,
                             unsigned* __restrict__ ovfcnt, int* __restrict__ ovf) {
    int e = blockIdx.x * blockDim.x + threadIdx.x;
    if (e >= NEDGES) return;
    int d = dst[e];
    unsigned slot = atomicAdd(&cnt[d], 1u);
    if (slot < CAP) {
        csr[(size_t)d * CAP + slot] = src[e];
    } else {
        unsigned o = atomicAdd(ovfcnt, 1u);
        if (o < OVFCAP) { ovf[2*o] = src[e]; ovf[2*o+1] = d; }
    }
}

// ------- fused layer: bf16 gather-aggregate into LDS, 64x64 GEMM + BN + ELU ---------
__global__ __launch_bounds__(256, 4) void layer_fused(
        const unsigned* __restrict__ hb, const unsigned* __restrict__ cnt,
        const int* __restrict__ csr, const unsigned* __restrict__ ovfcnt,
        const int* __restrict__ ovf,
        const float* __restrict__ Ws, const float* __restrict__ bs,
        const float* __restrict__ gammas, const float* __restrict__ betas,
        const float* __restrict__ means, const float* __restrict__ vars_,
        int layer, unsigned* __restrict__ outb) {
    __shared__ float Ml[TN][68];
    __shared__ float Wl[HDIM][68];
    int tid = threadIdx.x;

    // stage W (64x64 fp32), coalesced float4
    const float4* Wg4 = (const float4*)(Ws + (size_t)layer*HDIM*HDIM);
    #pragma unroll
    for (int r = 0; r < 4; ++r) {
        int f = tid + 256*r;
        int row = f >> 4, c4 = f & 15;
        *(float4*)&Wl[row][c4*4] = Wg4[f];
    }

    // aggregate: 8-lane group per node row, uint4 (8 bf16) per lane
    int base = blockIdx.x * TN;
    int grp = tid >> 3;               // 0..31
    int sub = tid & 7;                // 16B column chunk
    const uint4* h4 = (const uint4*)hb;
    #pragma unroll
    for (int i = 0; i < 2; ++i) {
        int row = grp + 32*i;
        int node = base + row;
        float a0=0,a1=0,a2=0,a3=0,a4=0,a5=0,a6=0,a7=0;
        if (node < NNODES) {
            unsigned deg = cnt[node]; if (deg > CAP) deg = CAP;
            const int* ed = csr + (size_t)node * CAP;
            unsigned e = 0;
            for (; e + 4 <= deg; e += 4) {
                int s0 = ed[e], s1 = ed[e+1], s2 = ed[e+2], s3 = ed[e+3];
                uint4 v0 = h4[(size_t)s0*8 + sub];
                uint4 v1 = h4[(size_t)s1*8 + sub];
                uint4 v2 = h4[(size_t)s2*8 + sub];
                uint4 v3 = h4[(size_t)s3*8 + sub];
                a0 += bflo(v0.x)+bflo(v1.x)+bflo(v2.x)+bflo(v3.x);
                a1 += bfhi(v0.x)+bfhi(v1.x)+bfhi(v2.x)+bfhi(v3.x);
                a2 += bflo(v0.y)+bflo(v1.y)+bflo(v2.y)+bflo(v3.y);
                a3 += bfhi(v0.y)+bfhi(v1.y)+bfhi(v2.y)+bfhi(v3.y);
                a4 += bflo(v0.z)+bflo(v1.z)+bflo(v2.z)+bflo(v3.z);
                a5 += bfhi(v0.z)+bfhi(v1.z)+bfhi(v2.z)+bfhi(v3.z);
                a6 += bflo(v0.w)+bflo(v1.w)+bflo(v2.w)+bflo(v3.w);
                a7 += bfhi(v0.w)+bfhi(v1.w)+bfhi(v2.w)+bfhi(v3.w);
            }
            for (; e < deg; ++e) {
                uint4 v = h4[(size_t)ed[e]*8 + sub];
                a0 += bflo(v.x); a1 += bfhi(v.x);
                a2 += bflo(v.y); a3 += bfhi(v.y);
                a4 += bflo(v.z); a5 += bfhi(v.z);
                a6 += bflo(v.w); a7 += bfhi(v.w);
            }
        }
        *(float4*)&Ml[row][sub*8]     = make_float4(a0,a1,a2,a3);
        *(float4*)&Ml[row][sub*8 + 4] = make_float4(a4,a5,a6,a7);
    }
    __syncthreads();

    // overflow edges (normally zero)
    unsigned novf = *ovfcnt; if (novf > OVFCAP) novf = OVFCAP;
    if (novf) {
        for (unsigned e = tid; e < novf; e += 256) {
            int s = ovf[2*e], d = ovf[2*e+1];
            if (d >= base && d < base + TN && d < NNODES) {
                const uint4* hr = h4 + (size_t)s*8;
                #pragma unroll
                for (int q = 0; q < 8; ++q) {
                    uint4 v = hr[q];
                    atomicAdd(&Ml[d-base][q*8+0], bflo(v.x));
                    atomicAdd(&Ml[d-base][q*8+1], bfhi(v.x));
                    atomicAdd(&Ml[d-base][q*8+2], bflo(v.y));
                    atomicAdd(&Ml[d-base][q*8+3], bfhi(v.y));
                    atomicAdd(&Ml[d-base][q*8+4], bflo(v.z));
                    atomicAdd(&Ml[d-base][q*8+5], bfhi(v.z));
                    atomicAdd(&Ml[d-base][q*8+6], bflo(v.w));
                    atomicAdd(&Ml[d-base][q*8+7], bfhi(v.w));
                }
            }
        }
        __syncthreads();
    }

    // GEMM phase: 4x4 per thread
    int tx = tid & 15;
    int ty = tid >> 4;
    float acc[4][4];
    #pragma unroll
    for (int i = 0; i < 4; ++i)
        #pragma unroll
        for (int j = 0; j < 4; ++j) acc[i][j] = 0.f;

    #pragma unroll 4
    for (int k4 = 0; k4 < 16; ++k4) {
        float4 b0 = *(const float4*)&Wl[4*k4+0][ty*4];
        float4 b1 = *(const float4*)&Wl[4*k4+1][ty*4];
        float4 b2 = *(const float4*)&Wl[4*k4+2][ty*4];
        float4 b3 = *(const float4*)&Wl[4*k4+3][ty*4];
        #pragma unroll
        for (int i = 0; i < 4; ++i) {
            float4 a = *(const float4*)&Ml[tx + 16*i][k4*4];
            acc[i][0] += a.x*b0.x + a.y*b1.x + a.z*b2.x + a.w*b3.x;
            acc[i][1] += a.x*b0.y + a.y*b1.y + a.z*b2.y + a.w*b3.y;
            acc[i][2] += a.x*b0.z + a.y*b1.z + a.z*b2.z + a.w*b3.z;
            acc[i][3] += a.x*b0.w + a.y*b1.w + a.z*b2.w + a.w*b3.w;
        }
    }

    // epilogue: BN folded scale/shift + ELU, pack bf16
    float sc[4], sh[4];
    #pragma unroll
    for (int j = 0; j < 4; ++j) {
        int c = ty*4 + j;
        float b  = bs[layer*HDIM + c];
        float gm = gammas[layer*HDIM + c];
        float be = betas[layer*HDIM + c];
        float mu = means[layer*HDIM + c];
        float vv = vars_[layer*HDIM + c];
        float s  = gm * rsqrtf(vv + BN_EPS);
        sc[j] = s;
        sh[j] = (b - mu) * s + be;
    }
    #pragma unroll
    for (int i = 0; i < 4; ++i) {
        int node = base + tx + 16*i;
        if (node >= NNODES) continue;
        float y0 = acc[i][0]*sc[0] + sh[0]; y0 = (y0 > 0.f) ? y0 : expm1f(y0);
        float y1 = acc[i][1]*sc[1] + sh[1]; y1 = (y1 > 0.f) ? y1 : expm1f(y1);
        float y2 = acc[i][2]*sc[2] + sh[2]; y2 = (y2 > 0.f) ? y2 : expm1f(y2);
        float y3 = acc[i][3]*sc[3] + sh[3]; y3 = (y3 > 0.f) ? y3 : expm1f(y3);
        uint2 o;
        o.x = f2bf(y0) | (f2bf(y1) << 16);
        o.y = f2bf(y2) | (f2bf(y3) << 16);
        *(uint2*)((unsigned*)outb + (size_t)node*32 + ty*2) = o;
    }
}

// ---------------- logits -> entropy per node (8 lanes/node) + block-max -------------
__global__ __launch_bounds__(256) void classify_bf16(
        const uint4* __restrict__ h4, const float* __restrict__ Wc,
        const float* __restrict__ bc, float* __restrict__ Hent,
        unsigned* __restrict__ maxH) {
    __shared__ float Wl[HDIM*11];     // stride 11: conflict-light
    __shared__ float bl[CDIM];
    __shared__ float wmax[4];
    int tid = threadIdx.x;
    for (int idx = tid; idx < HDIM*CDIM; idx += 256)
        Wl[(idx/CDIM)*11 + (idx%CDIM)] = Wc[idx];
    if (tid < CDIM) bl[tid] = bc[tid];
    __syncthreads();

    int node = blockIdx.x * 32 + (tid >> 3);
    int sub  = tid & 7;
    uint4 v = h4[(size_t)node*8 + sub];
    float h[8];
    h[0]=bflo(v.x); h[1]=bfhi(v.x); h[2]=bflo(v.y); h[3]=bfhi(v.y);
    h[4]=bflo(v.z); h[5]=bfhi(v.z); h[6]=bflo(v.w); h[7]=bfhi(v.w);

    float lg[CDIM];
    #pragma unroll
    for (int c = 0; c < CDIM; ++c) lg[c] = 0.f;
    #pragma unroll
    for (int k = 0; k < 8; ++k) {
        const float* wr = &Wl[(sub*8 + k)*11];
        float x = h[k];
        #pragma unroll
        for (int c = 0; c < CDIM; ++c) lg[c] += x * wr[c];
    }
    #pragma unroll
    for (int m = 1; m < 8; m <<= 1)
        #pragma unroll
        for (int c = 0; c < CDIM; ++c) lg[c] += __shfl_xor(lg[c], m, 64);
    #pragma unroll
    for (int c = 0; c < CDIM; ++c) lg[c] += bl[c];

    float mx = lg[0];
    #pragma unroll
    for (int c = 1; c < CDIM; ++c) mx = fmaxf(mx, lg[c]);
    float se = 0.f, dot = 0.f;
    #pragma unroll
    for (int c = 0; c < CDIM; ++c) { float e = expf(lg[c]-mx); se += e; dot += e*lg[c]; }
    float Hv = (mx + logf(se)) - dot/se;
    Hv = fmaxf(Hv, 0.f);
    if (sub == 0) Hent[node] = Hv;

    // block max -> 1 atomic
    float m8 = Hv;
    #pragma unroll
    for (int m = 8; m < 64; m <<= 1) m8 = fmaxf(m8, __shfl_xor(m8, m, 64));
    if ((tid & 63) == 0) wmax[tid >> 6] = m8;
    __syncthreads();
    if (tid == 0) {
        float mm = fmaxf(fmaxf(wmax[0], wmax[1]), fmaxf(wmax[2], wmax[3]));
        atomicMax(maxH, __float_as_uint(mm));
    }
}

// ---------------- per-graph lambda-weighted pooling + final classify ----------------
__global__ void pool_final_bf16(const unsigned* __restrict__ H2, const float* __restrict__ Hent,
                                const unsigned* __restrict__ maxH, const int* __restrict__ n2g,
                                const float* __restrict__ Wc, const float* __restrict__ bc,
                                float* __restrict__ out) {
    __shared__ float partial[8][HDIM];
    __shared__ float pooled[HDIM];
    int g = blockIdx.x;
    int tid = threadIdx.x;

    int lo = 0, hi = NNODES;
    while (lo < hi) { int mid = (lo+hi) >> 1; if (n2g[mid] < g) lo = mid+1; else hi = mid; }
    int start = lo;
    hi = NNODES;
    while (lo < hi) { int mid = (lo+hi) >> 1; if (n2g[mid] < g+1) lo = mid+1; else hi = mid; }
    int end = lo;

    float invMax = 1.0f / __uint_as_float(*maxH);
    int half = tid >> 5, l = tid & 31;
    float ax = 0.f, ay = 0.f;
    for (int i = start + half; i < end; i += 8) {
        float lam = 1.0f - Hent[i] * invMax;
        unsigned u = H2[(size_t)i*32 + l];
        ax += lam * bflo(u);
        ay += lam * bfhi(u);
    }
    partial[half][2*l]   = ax;
    partial[half][2*l+1] = ay;
    __syncthreads();
    if (tid < HDIM) {
        float s = 0.f;
        #pragma unroll
        for (int hh = 0; hh < 8; ++hh) s += partial[hh][tid];
        pooled[tid] = s;
    }
    __syncthreads();
    if (tid < CDIM) {
        float s = bc[tid];
        for (int k = 0; k < HDIM; ++k) s += pooled[k] * Wc[k*CDIM + tid];
        out[g*CDIM + tid] = s;
    }
}

extern "C" void kernel_launch(void* const* d_in, const int* in_sizes, int n_in,
                              void* d_out, int out_size, void* d_ws, size_t ws_size,
                              hipStream_t stream) {
    const float* feat  = (const float*)d_in[0];
    const int*   src   = (const int*)d_in[1];
    const int*   dst   = (const int*)d_in[2];
    const int*   n2g   = (const int*)d_in[3];
    const float* Ws    = (const float*)d_in[4];
    const float* bs    = (const float*)d_in[5];
    const float* gam   = (const float*)d_in[6];
    const float* bet   = (const float*)d_in[7];
    const float* mea   = (const float*)d_in[8];
    const float* var_  = (const float*)d_in[9];
    const float* Wc    = (const float*)d_in[10];
    const float* bc    = (const float*)d_in[11];
    float* out = (float*)d_out;

    char* ws = (char*)d_ws;
    size_t off = 0;
    auto take = [&](size_t bytes) {
        char* p = ws + off;
        off += (bytes + 255) & ~(size_t)255;
        return p;
    };

    unsigned* cnt    = (unsigned*)take((size_t)NNODES*4);
    unsigned* ovfcnt = (unsigned*)take(4);
    unsigned* maxH   = (unsigned*)take(4);
    int*      ovf    = (int*)take((size_t)OVFCAP*2*4);
    float*    Hent   = (float*)take((size_t)NNODES*4);
    unsigned* featb  = (unsigned*)take((size_t)NNODES*HDIM*2);
    unsigned* HA     = (unsigned*)take((size_t)NNODES*HDIM*2);
    unsigned* HB     = (unsigned*)take((size_t)NNODES*HDIM*2);
    int*      csr    = (int*)take((size_t)NNODES*CAP*4);

    hipMemsetAsync(cnt, 0, (size_t)NNODES*4, stream);
    hipMemsetAsync(ovfcnt, 0, 4, stream);
    hipMemsetAsync(maxH, 0, 4, stream);

    cvt_feat<<<(NNODES*HDIM/8 + 255)/256, 256, 0, stream>>>((const float4*)feat, (uint4*)featb);
    fill_buckets<<<(NEDGES+255)/256, 256, 0, stream>>>(src, dst, cnt, csr, ovfcnt, ovf);

    int grid = (NNODES + TN - 1) / TN;
    layer_fused<<<grid, 256, 0, stream>>>(featb, cnt, csr, ovfcnt, ovf,
                                          Ws, bs, gam, bet, mea, var_, 0, HA);
    layer_fused<<<grid, 256, 0, stream>>>(HA, cnt, csr, ovfcnt, ovf,
                                          Ws, bs, gam, bet, mea, var_, 1, HB);
    layer_fused<<<grid, 256, 0, stream>>>(HB, cnt, csr, ovfcnt, ovf,
                                          Ws, bs, gam, bet, mea, var_, 2, HA);

    classify_bf16<<<(NNODES+31)/32, 256, 0, stream>>>((const uint4*)HA, Wc, bc, Hent, maxH);
    pool_final_bf16<<<NGRAPH, 256, 0, stream>>>(HA, Hent, maxH, n2g, Wc, bc, out);
}